// Round 10
// baseline (383.086 us; speedup 1.0000x reference)
//
#include <hip/hip_runtime.h>

#define L 4800
#define S 4800
#define C 256
#define NB 2
#define THRV 0.2f
#define SCALE 0.0390625f   // 1/(sqrt(C))^2 / TEMP = 1/25.6
#define NST1 75            // 64-row strips (pass1)
#define NCC 3              // column chunks of 1600
#define CCW 1600
#define NT 64              // cols per B tile
#define NTILES 25          // CCW/NT
#define P2R 20             // rows per pass2 block
#define NST2 240           // L/P2R

typedef _Float16 f16;
typedef _Float16 f16x8 __attribute__((ext_vector_type(8)));
typedef float f32x4 __attribute__((ext_vector_type(4)));

typedef __attribute__((address_space(1))) const unsigned int g_as1;
typedef __attribute__((address_space(3))) unsigned int lds_as3;

__device__ __forceinline__ void gload_lds16(const void* g, void* l) {
    __builtin_amdgcn_global_load_lds((g_as1*)g, (lds_as3*)l, 16, 0, 0);
}

// ---------------- K0: f32 -> f16 feature conversion ----------------
__global__ __launch_bounds__(256) void k_convert(const float* __restrict__ a, const float* __restrict__ b,
                                                 f16* __restrict__ ah, f16* __restrict__ bh) {
    const int PER = NB * L * C / 4;
    int idx = blockIdx.x * 256 + threadIdx.x;
    const float4* src;
    unsigned long long* dst;
    int i;
    if (idx < PER) { src = reinterpret_cast<const float4*>(a); dst = reinterpret_cast<unsigned long long*>(ah); i = idx; }
    else           { src = reinterpret_cast<const float4*>(b); dst = reinterpret_cast<unsigned long long*>(bh); i = idx - PER; }
    float4 v = src[i];
    union { f16 h[4]; unsigned long long u; } p;
    p.h[0] = (f16)v.x; p.h[1] = (f16)v.y; p.h[2] = (f16)v.z; p.h[3] = (f16)v.w;
    dst[i] = p.u;
}

// ===================== PASS 1: GEMM (A in regs, B dbuf LDS) -> E f16 + atomic row/col sums =====================
// grid (NST1, NCC, NB), 256 thr. Block: 64 rows x 1600 cols, K=256. LDS: B dbuf 2x32KB only.
__global__ __launch_bounds__(256) void k_pass1(const f16* __restrict__ f0h, const f16* __restrict__ f1h,
                                               f16* __restrict__ E, float* __restrict__ rowSum,
                                               float* __restrict__ colSum) {
    __shared__ __align__(16) unsigned char lds[65536];
    const int strip = blockIdx.x, cc = blockIdx.y, n = blockIdx.z;
    const int tid = threadIdx.x, lane = tid & 63, w = tid >> 6;
    const int fr = lane & 15, kg = lane >> 4;
    const int jbase = cc * CCW;

    // stage B tile 0 into buf0 (pre-swizzled source, linear dest)
    const f16* gBbase = f1h + ((size_t)n * S + jbase) * C;
    {
        const uint4* gBt = reinterpret_cast<const uint4*>(gBbase);
#pragma unroll
        for (int i = 0; i < 8; ++i) {
            int q = (w * 8 + i) * 64 + lane;
            int r = q >> 5, bcol = q & 31;
            gload_lds16(gBt + r * 32 + (bcol ^ (r & 7)), lds + (w * 8 + i) * 1024);
        }
    }
    // A fragments (64 rows) direct global -> registers, reused across all 25 tiles
    f16x8 a[4][8];
    const f16* Ab = f0h + ((size_t)n * L + strip * 64) * C;
#pragma unroll
    for (int mi = 0; mi < 4; ++mi)
#pragma unroll
        for (int ks = 0; ks < 8; ++ks)
            a[mi][ks] = *reinterpret_cast<const f16x8*>(Ab + (mi * 16 + fr) * C + ks * 32 + kg * 8);

    asm volatile("s_waitcnt vmcnt(0)" ::: "memory");
    __syncthreads();

    float rowAcc[16] = {};
    const int rowb = w * 16 + fr;
    f16* Ebase = E + ((size_t)n * L + strip * 64 + kg * 4) * S + jbase + w * 16 + fr;

    for (int t = 0; t < NTILES; ++t) {
        const int cur = t & 1;
        if (t < NTILES - 1) {
            const uint4* gBt = reinterpret_cast<const uint4*>(gBbase + (size_t)(t + 1) * NT * C);
            unsigned char* dst = lds + (cur ^ 1) * 32768;
#pragma unroll
            for (int i = 0; i < 8; ++i) {
                int q = (w * 8 + i) * 64 + lane;
                int r = q >> 5, bcol = q & 31;
                gload_lds16(gBt + r * 32 + (bcol ^ (r & 7)), dst + (w * 8 + i) * 1024);
            }
            // queue (old->new): [stage_t 8][epi_{t-1}: 16 stores + 1 atomic][stage_{t+1} 8] -> wait<=25 drains stage_t
            asm volatile("s_waitcnt vmcnt(25)" ::: "memory");
        } else {
            // queue: [stage_24 8][epi_23 17] -> wait<=17 drains stage_24
            asm volatile("s_waitcnt vmcnt(17)" ::: "memory");
        }
        __builtin_amdgcn_s_barrier();
        asm volatile("" ::: "memory");

        const unsigned char* Bb = lds + cur * 32768;
        f32x4 acc[4] = {};
#pragma unroll
        for (int ks = 0; ks < 8; ++ks) {
            f16x8 bf = *reinterpret_cast<const f16x8*>(Bb + (rowb * 32 + ((ks * 4 + kg) ^ (rowb & 7))) * 16);
#pragma unroll
            for (int mi = 0; mi < 4; ++mi)
                acc[mi] = __builtin_amdgcn_mfma_f32_16x16x32_f16(a[mi][ks], bf, acc[mi], 0, 0, 0);
        }

        // epilogue: e = exp(sim*scale); store E f16 (16 stores), row/col partial sums
        float colv = 0.f;
        f16* ep = Ebase + t * NT;
#pragma unroll
        for (int mi = 0; mi < 4; ++mi)
#pragma unroll
            for (int r4 = 0; r4 < 4; ++r4) {
                float ef = __expf(acc[mi][r4] * SCALE);
                rowAcc[mi * 4 + r4] += ef;
                colv += ef;
                ep[(size_t)(mi * 16 + r4) * S] = (f16)ef;
            }
        colv += __shfl_xor(colv, 16);
        colv += __shfl_xor(colv, 32);
        if (lane < 16)
            unsafeAtomicAdd(&colSum[(size_t)n * S + jbase + t * NT + w * 16 + lane], colv);
        asm volatile("" ::: "memory");
        __builtin_amdgcn_s_barrier();
    }

    // row sums: reduce over the 16 col-lanes (fr), then atomic add (4 waves x 3 cc chunks contribute)
#pragma unroll
    for (int o = 1; o < 16; o <<= 1)
#pragma unroll
        for (int i = 0; i < 16; ++i) rowAcc[i] += __shfl_xor(rowAcc[i], o);
    if (fr == 0) {
#pragma unroll
        for (int mi = 0; mi < 4; ++mi)
#pragma unroll
            for (int r4 = 0; r4 < 4; ++r4)
                unsafeAtomicAdd(&rowSum[(size_t)n * L + strip * 64 + mi * 16 + kg * 4 + r4],
                                rowAcc[mi * 4 + r4]);
    }
}

// ===================== PASS 2: stream E -> conf + row argmax + col atomicMax =====================
// grid (NST2, NB), 256 thr. Block: 20 rows x all 4800 cols. No GEMM, pure BW.
__global__ __launch_bounds__(256) void k_pass2(const f16* __restrict__ E,
                                               const float* __restrict__ rowSum, const float* __restrict__ colSum,
                                               float* __restrict__ conf,
                                               float* __restrict__ rowVal, int* __restrict__ rowArg,
                                               int* __restrict__ colMaxI) {
    __shared__ float icsL[S];
    __shared__ float irsL[P2R];
    __shared__ float rvL[4][P2R];
    __shared__ int rjL[4][P2R];
    const int strip = blockIdx.x, n = blockIdx.y;
    const int r0 = strip * P2R;
    const int tid = threadIdx.x;
    for (int c = tid; c < S; c += 256) icsL[c] = 1.0f / colSum[(size_t)n * S + c];
    if (tid < P2R) irsL[tid] = 1.0f / rowSum[(size_t)n * L + r0 + tid];
    __syncthreads();

    float bestV[P2R]; int bestJ[P2R];
#pragma unroll
    for (int r = 0; r < P2R; ++r) { bestV[r] = -1.0f; bestJ[r] = 0; }

    const f16* Eb = E + ((size_t)n * L + r0) * S;
    float* Cb = conf + ((size_t)n * L + r0) * S;

    for (int c = tid; c < S / 8; c += 256) {
        const int j0 = c * 8;
        float ics[8];
#pragma unroll
        for (int k = 0; k < 8; ++k) ics[k] = icsL[j0 + k];
        float colm[8];
#pragma unroll
        for (int k = 0; k < 8; ++k) colm[k] = 0.f;
#pragma unroll
        for (int r = 0; r < P2R; ++r) {
            f16x8 ev = *reinterpret_cast<const f16x8*>(Eb + (size_t)r * S + j0);
            const float irs = irsL[r];
            float cf[8];
#pragma unroll
            for (int k = 0; k < 8; ++k) {
                float e = (float)ev[k];
                cf[k] = (e * e * irs) * ics[k];
                colm[k] = fmaxf(colm[k], cf[k]);
                if (cf[k] > bestV[r]) { bestV[r] = cf[k]; bestJ[r] = j0 + k; }
            }
            float4 w0 = {cf[0], cf[1], cf[2], cf[3]};
            float4 w1 = {cf[4], cf[5], cf[6], cf[7]};
            float4* cp = reinterpret_cast<float4*>(Cb + (size_t)r * S + j0);
            cp[0] = w0; cp[1] = w1;
        }
#pragma unroll
        for (int k = 0; k < 8; ++k)
            atomicMax(&colMaxI[(size_t)n * S + j0 + k], __float_as_int(colm[k]));
    }

    // block-reduce per-row best (tie -> min j)
    const int lane = tid & 63, wv = tid >> 6;
#pragma unroll
    for (int r = 0; r < P2R; ++r) {
        float v = bestV[r]; int j = bestJ[r];
#pragma unroll
        for (int o = 1; o < 64; o <<= 1) {
            float ov = __shfl_xor(v, o); int oj = __shfl_xor(j, o);
            if (ov > v || (ov == v && oj < j)) { v = ov; j = oj; }
        }
        if (lane == 0) { rvL[wv][r] = v; rjL[wv][r] = j; }
    }
    __syncthreads();
    if (tid < P2R) {
        float v = rvL[0][tid]; int j = rjL[0][tid];
#pragma unroll
        for (int q = 1; q < 4; ++q) {
            float ov = rvL[q][tid]; int oj = rjL[q][tid];
            if (ov > v || (ov == v && oj < j)) { v = ov; j = oj; }
        }
        rowVal[(size_t)n * L + r0 + tid] = v;
        rowArg[(size_t)n * L + r0 + tid] = j;
    }
}

// ---------------- final: threshold + border + mutual-NN ----------------
__global__ __launch_bounds__(256) void k_final(const float* __restrict__ rowVal, const int* __restrict__ rowArg,
                                               const int* __restrict__ colMaxI,
                                               float* __restrict__ out_maskv, float* __restrict__ out_jids,
                                               float* __restrict__ out_mconf) {
    int idx = blockIdx.x * 256 + threadIdx.x;
    if (idx >= NB * L) return;
    int n = idx / L, i = idx % L;
    float v = rowVal[idx];
    int j = rowArg[idx];
    float cm = __int_as_float(colMaxI[(size_t)n * S + j]);
    int h0 = i / 80, w0 = i % 80;
    int h1 = j / 80, w1 = j % 80;
    bool ok = (v > THRV)
              && (h0 >= 2) && (h0 < 58) && (w0 >= 2) && (w0 < 78)
              && (h1 >= 2) && (h1 < 58) && (w1 >= 2) && (w1 < 78)
              && (v == cm);
    out_maskv[idx] = ok ? 1.0f : 0.0f;
    out_jids[idx]  = ok ? (float)j : 0.0f;
    out_mconf[idx] = ok ? v : 0.0f;
}

extern "C" void kernel_launch(void* const* d_in, const int* in_sizes, int n_in,
                              void* d_out, int out_size, void* d_ws, size_t ws_size,
                              hipStream_t stream) {
    const float* f0 = (const float*)d_in[0];
    const float* f1 = (const float*)d_in[1];
    float* out = (float*)d_out;
    char* ws = (char*)d_ws;

    // ws layout (bytes): ~102 MB total
    f16*   f0h     = (f16*)(ws + 0);             //  4,915,200
    f16*   f1h     = (f16*)(ws + 4915200);       //  4,915,200
    f16*   E       = (f16*)(ws + 9830400);       // 92,160,000 (NB*L*S f16)
    float* rowSum  = (float*)(ws + 101990400);   //     38,400 } zeroed
    float* colSum  = (float*)(ws + 102028800);   //     38,400 } by one
    int*   colMaxI = (int*)  (ws + 102067200);   //     38,400 } memset
    float* rowVal  = (float*)(ws + 102105600);   //     38,400
    int*   rowArg  = (int*)  (ws + 102144000);   //     38,400

    float* conf = out;
    float* out_maskv = out + (size_t)NB * L * S;
    float* out_jids  = out_maskv + NB * L;
    float* out_mconf = out_jids + NB * L;

    hipMemsetAsync(ws + 101990400, 0, 115200, stream);
    k_convert<<<4800, 256, 0, stream>>>(f0, f1, f0h, f1h);
    k_pass1<<<dim3(NST1, NCC, NB), 256, 0, stream>>>(f0h, f1h, E, rowSum, colSum);
    k_pass2<<<dim3(NST2, NB), 256, 0, stream>>>(E, rowSum, colSum, conf, rowVal, rowArg, colMaxI);
    k_final<<<(NB * L + 255) / 256, 256, 0, stream>>>(rowVal, rowArg, colMaxI,
                                                      out_maskv, out_jids, out_mconf);
}